// Round 7
// baseline (433.541 us; speedup 1.0000x reference)
//
#include <hip/hip_runtime.h>

#define BATCH 32
#define HDIM 224
#define WDIM 224
#define CDIM 3
#define KTOT (HDIM * WDIM * CDIM)   // 150528
#define HID 64
#define KC 256                       // k-stripe per block
#define NBLK1 (KTOT / KC)            // 588
#define PIX (HDIM * WDIM)            // 50176
#define BLK3 49                      // 256 thr * 4 px = 1024 px per block

// ---------------- Kernel 1: hacc += flat[:,kslice] @ w1[kslice,:] ------------
// NO LDS, NO barriers, NO phases. 4 independent waves per block; wave owns
// (8 batches x 256-k stripe). Lane: q=lane>>4 (k phase), h4=lane&15 (h group).
// Per 16-k chunk: 4 w1 dwordx4 + 8 broadcast flat dwordx4 = 12 independent
// loads feeding 128 FMAs; the 16-chunk loop is fully unrolled so the
// scheduler can hoist loads deep (vmcnt pipelining) within the VGPR cap.
__global__ __launch_bounds__(256, 4) void k1_gemm(const float* __restrict__ flat,
                                                  const float* __restrict__ w1,
                                                  float* __restrict__ hacc) {
    const int tid  = threadIdx.x;
    const int lane = tid & 63;
    const int wave = tid >> 6;
    const int q    = lane >> 4;                  // k phase 0..3
    const int h4   = lane & 15;                  // h group: hids h4*4..+4
    const int b0   = wave * 8;                   // wave's 8 batches
    const int k0   = blockIdx.x * KC;

    float4 acc[8];
#pragma unroll
    for (int b = 0; b < 8; ++b) acc[b] = make_float4(0.f, 0.f, 0.f, 0.f);

#pragma unroll
    for (int c = 0; c < KC / 16; ++c) {          // 16 chunks of 16 k
        const int kc = k0 + c * 16 + q * 4;      // lane's 4 k's this chunk

        float4 w4[4];
#pragma unroll
        for (int i = 0; i < 4; ++i)              // w1[kc+i][h4*4 .. +4]
            w4[i] = *(const float4*)(w1 + (size_t)(kc + i) * HID + h4 * 4);

        float4 x4[8];
#pragma unroll
        for (int b = 0; b < 8; ++b)              // flat[b0+b][kc .. +4]
            x4[b] = *(const float4*)(flat + (size_t)(b0 + b) * KTOT + kc);

#pragma unroll
        for (int b = 0; b < 8; ++b) {
            const float xs[4] = {x4[b].x, x4[b].y, x4[b].z, x4[b].w};
            float* A = (float*)&acc[b];
#pragma unroll
            for (int i = 0; i < 4; ++i) {
                const float* wf = (const float*)&w4[i];
#pragma unroll
                for (int h = 0; h < 4; ++h)
                    A[h] = fmaf(xs[i], wf[h], A[h]);
            }
        }
    }

    // 4 lanes (the 4 q-phases) add into each (b, h) -> TCC resolves.
#pragma unroll
    for (int b = 0; b < 8; ++b) {
        const float* A = (const float*)&acc[b];
#pragma unroll
        for (int h = 0; h < 4; ++h)
            atomicAdd(hacc + (b0 + b) * HID + h4 * 4 + h, A[h]);
    }
}

// -------- Kernel 3: head recompute + affine grid + bilinear sampling --------
__global__ __launch_bounds__(256) void k3_sample(const float* __restrict__ img,
                                                 const float* __restrict__ hacc,
                                                 const float* __restrict__ b1,
                                                 const float* __restrict__ w2,
                                                 const float* __restrict__ b2,
                                                 float* __restrict__ out) {
    const int b     = blockIdx.x / BLK3;
    const int strip = blockIdx.x - b * BLK3;
    const int tid   = threadIdx.x;

    __shared__ float sh[HID];
    __shared__ float sth[6];
    if (tid < HID)
        sh[tid] = tanhf(hacc[b * HID + tid] + b1[tid]);
    __syncthreads();
    if (tid < 6) {
        float s = b2[tid];
#pragma unroll
        for (int t = 0; t < HID; ++t)
            s = fmaf(sh[t], w2[t * 6 + tid], s);
        sth[tid] = tanhf(s);
    }
    __syncthreads();

    const float t0 = sth[0], t1 = sth[1], t2 = sth[2];
    const float t3 = sth[3], t4 = sth[4], t5 = sth[5];

    const float* base = img + (size_t)b * KTOT;
    const int pix0 = strip * 1024 + tid * 4;

    float res[12];
#pragma unroll
    for (int p = 0; p < 4; ++p) {
        const int pix = pix0 + p;
        const int i = pix / WDIM;
        const int j = pix - i * WDIM;

        const float xt = (2.0f * (float)j - (float)(WDIM - 1)) / (float)(WDIM - 1);
        const float yt = (2.0f * (float)i - (float)(HDIM - 1)) / (float)(HDIM - 1);

        const float xs = t0 * xt + t1 * yt + t2;
        const float ys = t3 * xt + t4 * yt + t5;

        const float x = 0.5f * (xs + 1.0f) * (float)(WDIM - 1);
        const float y = 0.5f * (ys + 1.0f) * (float)(HDIM - 1);

        const int x0 = (int)floorf(x);
        const int y0 = (int)floorf(y);

        const int x0c = min(max(x0, 0), WDIM - 1);
        const int x1c = min(max(x0 + 1, 0), WDIM - 1);
        const int y0c = min(max(y0, 0), HDIM - 1);
        const int y1c = min(max(y0 + 1, 0), HDIM - 1);

        // Reference computes weights from the CLIPPED corner coordinates.
        const float x0f = (float)x0c, x1f = (float)x1c;
        const float y0f = (float)y0c, y1f = (float)y1c;

        const float wa = (x1f - x) * (y1f - y);
        const float wb = (x1f - x) * (y - y0f);
        const float wc = (x - x0f) * (y1f - y);
        const float wd = (x - x0f) * (y - y0f);

        const float* pa = base + (size_t)(y0c * WDIM + x0c) * 3;
        const float* pb = base + (size_t)(y1c * WDIM + x0c) * 3;
        const float* pc = base + (size_t)(y0c * WDIM + x1c) * 3;
        const float* pd = base + (size_t)(y1c * WDIM + x1c) * 3;

#pragma unroll
        for (int c = 0; c < 3; ++c)
            res[p * 3 + c] = wa * pa[c] + wb * pb[c] + wc * pc[c] + wd * pd[c];
    }

    float4* po = (float4*)(out + (size_t)b * KTOT + (size_t)pix0 * 3);
    po[0] = make_float4(res[0], res[1], res[2],  res[3]);
    po[1] = make_float4(res[4], res[5], res[6],  res[7]);
    po[2] = make_float4(res[8], res[9], res[10], res[11]);
}

extern "C" void kernel_launch(void* const* d_in, const int* in_sizes, int n_in,
                              void* d_out, int out_size, void* d_ws, size_t ws_size,
                              hipStream_t stream) {
    const float* inputs = (const float*)d_in[0];
    const float* w1     = (const float*)d_in[1];
    const float* b1     = (const float*)d_in[2];
    const float* w2     = (const float*)d_in[3];
    const float* b2     = (const float*)d_in[4];
    float* out = (float*)d_out;

    float* hacc = (float*)d_ws;                  // 32*64 floats = 8 KB only

    hipMemsetAsync(hacc, 0, BATCH * HID * sizeof(float), stream);
    k1_gemm<<<NBLK1, 256, 0, stream>>>(inputs, w1, hacc);
    k3_sample<<<BATCH * BLK3, 256, 0, stream>>>(inputs, hacc, b1, w2, b2, out);
}

// Round 8
// 146.192 us; speedup vs baseline: 2.9656x; 2.9656x over previous
//
#include <hip/hip_runtime.h>

#define BATCH 32
#define HDIM 224
#define WDIM 224
#define CDIM 3
#define KTOT (HDIM * WDIM * CDIM)   // 150528
#define HID 64
#define KCHUNK 128
#define NBLK1 (KTOT / KCHUNK)       // 1176
#define PIX (HDIM * WDIM)           // 50176
#define BLK3 49                      // 256 thr * 4 px = 1024 px per block

// ---------------- Kernel 1: hacc += flat[:,kslice] @ w1[kslice,:] ------------
// R2 champion structure (45.6 us): 4 waves partition K, lane = hid, acc[32]
// batches/thread, 16 KB LDS flat staging, inline w1 loads (NONTEMPORAL: w1 is
// single-use, 2/3 of all bytes -> don't pollute L2), cross-wave LDS reduce,
// coalesced atomics into 8 KB hacc.
__global__ __launch_bounds__(256, 5) void k1_gemm(const float* __restrict__ flat,
                                                  const float* __restrict__ w1,
                                                  float* __restrict__ hacc) {
    __shared__ float smem[8192];                 // 32 KB dual-purpose
    const int tid  = threadIdx.x;
    const int lane = tid & 63;                   // hid
    const int wave = tid >> 6;
    const int k0   = blockIdx.x * KCHUNK;

    // --- Stage flat[32][k0..k0+128) into LDS (16 KB), coalesced float4 ---
#pragma unroll
    for (int t = 0; t < 4; ++t) {
        const int idx = tid + t * 256;           // 0..1023
        const int b   = idx >> 5;                // 0..31
        const int kq  = idx & 31;                // float4 index
        *(float4*)(&smem[b * 128 + kq * 4]) =
            *(const float4*)(flat + (size_t)b * KTOT + k0 + kq * 4);
    }
    __syncthreads();

    float acc[32];
#pragma unroll
    for (int j = 0; j < 32; ++j) acc[j] = 0.0f;

    const int kw = wave * 32;                    // wave's k-offset in chunk
#pragma unroll
    for (int kk = 0; kk < 32; kk += 4) {
        const int k = k0 + kw + kk;
        float w[4];
#pragma unroll
        for (int i = 0; i < 4; ++i)              // single-use stream: nt load
            w[i] = __builtin_nontemporal_load(w1 + (size_t)(k + i) * HID + lane);
#pragma unroll
        for (int bg = 0; bg < 4; ++bg) {
            float4 x[8];
#pragma unroll
            for (int j = 0; j < 8; ++j)
                x[j] = *(const float4*)(&smem[(bg * 8 + j) * 128 + kw + kk]);
#pragma unroll
            for (int i = 0; i < 4; ++i)
#pragma unroll
                for (int j = 0; j < 8; ++j)
                    acc[bg * 8 + j] = fmaf(((const float*)&x[j])[i], w[i],
                                           acc[bg * 8 + j]);
        }
    }
    __syncthreads();                             // flat slice fully consumed

    // --- Cross-wave reduce in LDS, then one coalesced atomic per element ---
#pragma unroll
    for (int j = 0; j < 32; ++j)
        smem[wave * 2048 + j * 64 + lane] = acc[j];
    __syncthreads();

#pragma unroll
    for (int t = 0; t < 8; ++t) {
        const int idx = tid + t * 256;           // 0..2047 = b*64+hid
        const float s = smem[idx] + smem[2048 + idx] +
                        smem[4096 + idx] + smem[6144 + idx];
        atomicAdd(hacc + idx, s);
    }
}

// -------- Kernel 3: head recompute + affine grid + bilinear sampling --------
__global__ __launch_bounds__(256) void k3_sample(const float* __restrict__ img,
                                                 const float* __restrict__ hacc,
                                                 const float* __restrict__ b1,
                                                 const float* __restrict__ w2,
                                                 const float* __restrict__ b2,
                                                 float* __restrict__ out) {
    const int b     = blockIdx.x / BLK3;
    const int strip = blockIdx.x - b * BLK3;
    const int tid   = threadIdx.x;

    __shared__ float sh[HID];
    __shared__ float sth[6];
    if (tid < HID)
        sh[tid] = tanhf(hacc[b * HID + tid] + b1[tid]);
    __syncthreads();
    if (tid < 6) {
        float s = b2[tid];
#pragma unroll
        for (int t = 0; t < HID; ++t)
            s = fmaf(sh[t], w2[t * 6 + tid], s);
        sth[tid] = tanhf(s);
    }
    __syncthreads();

    const float t0 = sth[0], t1 = sth[1], t2 = sth[2];
    const float t3 = sth[3], t4 = sth[4], t5 = sth[5];

    const float* base = img + (size_t)b * KTOT;
    const int pix0 = strip * 1024 + tid * 4;

    float res[12];
#pragma unroll
    for (int p = 0; p < 4; ++p) {
        const int pix = pix0 + p;
        const int i = pix / WDIM;
        const int j = pix - i * WDIM;

        const float xt = (2.0f * (float)j - (float)(WDIM - 1)) / (float)(WDIM - 1);
        const float yt = (2.0f * (float)i - (float)(HDIM - 1)) / (float)(HDIM - 1);

        const float xs = t0 * xt + t1 * yt + t2;
        const float ys = t3 * xt + t4 * yt + t5;

        const float x = 0.5f * (xs + 1.0f) * (float)(WDIM - 1);
        const float y = 0.5f * (ys + 1.0f) * (float)(HDIM - 1);

        const int x0 = (int)floorf(x);
        const int y0 = (int)floorf(y);

        const int x0c = min(max(x0, 0), WDIM - 1);
        const int x1c = min(max(x0 + 1, 0), WDIM - 1);
        const int y0c = min(max(y0, 0), HDIM - 1);
        const int y1c = min(max(y0 + 1, 0), HDIM - 1);

        // Reference computes weights from the CLIPPED corner coordinates.
        const float x0f = (float)x0c, x1f = (float)x1c;
        const float y0f = (float)y0c, y1f = (float)y1c;

        const float wa = (x1f - x) * (y1f - y);
        const float wb = (x1f - x) * (y - y0f);
        const float wc = (x - x0f) * (y1f - y);
        const float wd = (x - x0f) * (y - y0f);

        const float* pa = base + (size_t)(y0c * WDIM + x0c) * 3;
        const float* pb = base + (size_t)(y1c * WDIM + x0c) * 3;
        const float* pc = base + (size_t)(y0c * WDIM + x1c) * 3;
        const float* pd = base + (size_t)(y1c * WDIM + x1c) * 3;

#pragma unroll
        for (int c = 0; c < 3; ++c)
            res[p * 3 + c] = wa * pa[c] + wb * pb[c] + wc * pc[c] + wd * pd[c];
    }

    // out is never re-read: nontemporal stores keep L2 for the img gathers.
    float* po = out + (size_t)b * KTOT + (size_t)pix0 * 3;
    typedef float vf4 __attribute__((ext_vector_type(4)));
    vf4 v0 = {res[0], res[1], res[2],  res[3]};
    vf4 v1 = {res[4], res[5], res[6],  res[7]};
    vf4 v2 = {res[8], res[9], res[10], res[11]};
    __builtin_nontemporal_store(v0, (vf4*)(po + 0));
    __builtin_nontemporal_store(v1, (vf4*)(po + 4));
    __builtin_nontemporal_store(v2, (vf4*)(po + 8));
}

extern "C" void kernel_launch(void* const* d_in, const int* in_sizes, int n_in,
                              void* d_out, int out_size, void* d_ws, size_t ws_size,
                              hipStream_t stream) {
    const float* inputs = (const float*)d_in[0];
    const float* w1     = (const float*)d_in[1];
    const float* b1     = (const float*)d_in[2];
    const float* w2     = (const float*)d_in[3];
    const float* b2     = (const float*)d_in[4];
    float* out = (float*)d_out;

    float* hacc = (float*)d_ws;                  // 32*64 floats = 8 KB only

    hipMemsetAsync(hacc, 0, BATCH * HID * sizeof(float), stream);
    k1_gemm<<<NBLK1, 256, 0, stream>>>(inputs, w1, hacc);
    k3_sample<<<BATCH * BLK3, 256, 0, stream>>>(inputs, hacc, b1, w2, b2, out);
}